// Round 1
// 1787.159 us; speedup vs baseline: 1.0514x; 1.0514x over previous
//
#include <hip/hip_runtime.h>

typedef unsigned short u16;
typedef __attribute__((ext_vector_type(8))) short bf16x8;   // 8 bf16 in 4 VGPRs
typedef __attribute__((ext_vector_type(4))) float f32x4;

#define MFMA16(a, b, c) __builtin_amdgcn_mfma_f32_16x16x32_bf16((a), (b), (c), 0, 0, 0)

// async global->LDS, 16B per lane; LDS dest = wave-uniform base + lane*16
#define GLL(gp, lp)                                                         \
  __builtin_amdgcn_global_load_lds(                                         \
      (const __attribute__((address_space(1))) void*)(const void*)(gp),     \
      (__attribute__((address_space(3))) void*)(void*)(lp), 16, 0, 0)

__device__ __forceinline__ u16 f2bf(float f) {
  union { float f; unsigned u; } c; c.f = f;
  unsigned r = c.u + 0x7FFFu + ((c.u >> 16) & 1u);   // RNE
  return (u16)(r >> 16);
}

// ---------------- fp32 -> bf16 conversion (vectorized) ----------------
__global__ __launch_bounds__(256) void cvt_bf16_kernel(
    const float* __restrict__ in, u16* __restrict__ out, int n4) {
  int i = blockIdx.x * 256 + threadIdx.x;
  if (i < n4) {
    float4 v = ((const float4*)in)[i];
    ushort4 o;
    o.x = f2bf(v.x); o.y = f2bf(v.y); o.z = f2bf(v.z); o.w = f2bf(v.w);
    ((ushort4*)out)[i] = o;
  }
}

// ---------------- GEMM: C[m,n] = sum_k A[m,k]*Bw[n,k] + bias[n] ----------------
// M=8192 (64*128), N=1024 (8*128), K=1024. A,Bw bf16 row-major [*,1024].
// MODE 0: store bf16 to [b,h,s,d]   (Q,K)    m=b*2048+s, n=h*64+d
// MODE 2: store bf16 to [b,h,d,s]   (V^T) via LDS-transposed coalesced epilogue
// MODE 3: store fp32 to row-major [m,1024]   (final output)
template <int MODE>
__global__ __launch_bounds__(256) void gemm_bt_kernel(
    const u16* __restrict__ A, const u16* __restrict__ Bw,
    const float* __restrict__ bias, void* __restrict__ Cout) {
  constexpr int Kd = 1024;
  __shared__ u16 sA[128 * 32];
  __shared__ u16 sB[128 * 32];
  const int t = threadIdx.x;
  // XCD-aware swizzle: 512 blocks = 8 XCDs x 64; XCD g owns bx in [g*8, g*8+8)
  const int wg = blockIdx.x + (blockIdx.y << 6);
  const int swz = ((wg & 7) << 6) | (wg >> 3);
  const int m0 = (swz >> 3) * 128;
  const int n0 = (swz & 7) * 128;
  const int w = t >> 6, lane = t & 63, lo = lane & 15, qd = lane >> 4;

  f32x4 acc[4][4];
  for (int i = 0; i < 4; i++)
    for (int j = 0; j < 4; j++) acc[i][j] = (f32x4){0.f, 0.f, 0.f, 0.f};

  // staging: chunk c covers row c>>2, cols (c&3)*8..+7 ; thread t does c=t and c=t+256
  const int r0 = t >> 2, q0 = (t & 3) * 8;
  const u16* gA0 = A + (size_t)(m0 + r0) * Kd + q0;
  const u16* gA1 = A + (size_t)(m0 + r0 + 64) * Kd + q0;
  const u16* gB0 = Bw + (size_t)(n0 + r0) * Kd + q0;
  const u16* gB1 = Bw + (size_t)(n0 + r0 + 64) * Kd + q0;
  u16* lA0 = &sA[(t & ~63) * 8];
  u16* lA1 = &sA[((t + 256) & ~63) * 8];
  u16* lB0 = &sB[(t & ~63) * 8];
  u16* lB1 = &sB[((t + 256) & ~63) * 8];

  const int am = (w & 1) * 64, bn = (w >> 1) * 64;

  for (int kb = 0; kb < Kd; kb += 32) {
    GLL(gA0 + kb, lA0);
    GLL(gA1 + kb, lA1);
    GLL(gB0 + kb, lB0);
    GLL(gB1 + kb, lB1);
    __syncthreads();
    bf16x8 af[4], bfv[4];
    for (int i = 0; i < 4; i++)
      af[i] = *(const bf16x8*)&sA[(am + i * 16 + lo) * 32 + qd * 8];
    for (int j = 0; j < 4; j++)
      bfv[j] = *(const bf16x8*)&sB[(bn + j * 16 + lo) * 32 + qd * 8];
    for (int i = 0; i < 4; i++)
      for (int j = 0; j < 4; j++) acc[i][j] = MFMA16(af[i], bfv[j], acc[i][j]);
    __syncthreads();
  }

  if constexpr (MODE == 2) {
    // LDS-transposed epilogue: stage [n_local][m_local] bf16, then store
    // coalesced runs along s.  Old path did 2B stores at 4KB lane stride.
    __shared__ u16 sT[64 * 136];   // stride 136 u16 = 272B, 16B-aligned rows
    const int bb = m0 >> 11;       // batch constant per block (128 | 2048)
    const int s0 = m0 & 2047;
    const int h0 = n0 >> 6;
    for (int half = 0; half < 2; ++half) {
      __syncthreads();
      if ((w >> 1) == half) {      // waves whose bn == half*64
        for (int j = 0; j < 4; j++) {
          const float bval = bias[n0 + half * 64 + j * 16 + lo];
          for (int i = 0; i < 4; i++)
            for (int r = 0; r < 4; r++)
              sT[(j * 16 + lo) * 136 + am + i * 16 + qd * 4 + r] =
                  f2bf(acc[i][j][r] + bval);
        }
      }
      __syncthreads();
      // copy 64 rows (d = nr) x 128 u16 (s run) to global: [b,h,d,s]
      const int nr = t >> 2;
      u16* dst = (u16*)Cout +
                 ((size_t)((bb * 16 + h0 + half) * 64 + nr)) * 2048 + s0;
      for (int c = 0; c < 4; ++c) {
        const int ch = (t & 3) + c * 4;   // 16B chunk index 0..15
        *(uint4*)(dst + ch * 8) = *(const uint4*)(&sT[nr * 136 + ch * 8]);
      }
    }
  } else {
    for (int i = 0; i < 4; i++)
      for (int j = 0; j < 4; j++) {
        const int n = n0 + bn + j * 16 + lo;
        const float bval = bias[n];
        for (int r = 0; r < 4; r++) {
          const int m = m0 + am + i * 16 + qd * 4 + r;
          float v = acc[i][j][r] + bval;
          if constexpr (MODE == 3) {
            ((float*)Cout)[(size_t)m * 1024 + n] = v;
          } else {  // MODE 0: [b,h,s,d]
            const int bb = m >> 11, s = m & 2047, h = n >> 6, d = n & 63;
            ((u16*)Cout)[((size_t)(bb * 16 + h) * 2048 + s) * 64 + d] = f2bf(v);
          }
        }
      }
  }
}

// ---------------- zero the strictly-masked attn region ----------------
// For row r the attn kernel writes cols [0, kz(r)); this fills [kz(r), 2048).
// Pure streaming stores at write-BW instead of inside the latency-bound kernel.
__global__ __launch_bounds__(256) void zero_upper_kernel(float* __restrict__ attn) {
  const int t = threadIdx.x, w = t >> 6, lane = t & 63;
  const int row = blockIdx.x * 4 + w;
  float* rowp = attn + ((size_t)blockIdx.y * 2048 + row) * 2048;
  const int kz = ((((row >> 4) << 4) + 47) >> 5) << 5;   // == kcend of row's wave
  const float4 z4 = make_float4(0.f, 0.f, 0.f, 0.f);
  for (int c = kz + lane * 4; c < 2048; c += 256) *(float4*)(rowp + c) = z4;
}

// ---------------- fused causal attention ----------------
// grid: (32 qtiles, 64 b*h), XCD-swizzled so each XCD owns 8 bh (K+Vt = 4MB = L2).
// block 256 = 4 waves; wave w owns q-rows qt*64+w*16 .. +15.
// Q,K: [b,h,s,64] bf16 ; Vt: [b,h,64,s] bf16 ; attn fp32 ; ctx bf16 [8192,1024]
__global__ __launch_bounds__(256) void attn_fused_kernel(
    const u16* __restrict__ Q, const u16* __restrict__ K,
    const u16* __restrict__ Vt, float* __restrict__ attn,
    u16* __restrict__ ctx) {
  __shared__ u16 Plds[4][16 * 40];  // per-wave P staging, stride 40 kills conflicts
  const int wg = blockIdx.x + (blockIdx.y << 5);          // 0..2047
  const int swz = ((wg & 7) << 8) | (wg >> 3);            // bijective, 2048 = 8*256
  const int qt = swz & 31, bh = swz >> 5;
  const int t = threadIdx.x, w = t >> 6, lane = t & 63, lo = lane & 15, qd = lane >> 4;
  const u16* Qh = Q + (size_t)bh * 2048 * 64;
  const u16* Kh = K + (size_t)bh * 2048 * 64;
  const u16* Vh = Vt + (size_t)bh * 64 * 2048;
  float* Ah = attn + (size_t)bh * 2048 * 2048;
  const int qrow0 = qt * 64 + w * 16;
  const float scale2 = 0.125f * 1.44269504088896f;  // log2(e)/sqrt(64)

  bf16x8 aq0 = *(const bf16x8*)&Qh[(qrow0 + lo) * 64 + qd * 8];
  bf16x8 aq1 = *(const bf16x8*)&Qh[(qrow0 + lo) * 64 + 32 + qd * 8];

  // ---- phase 1: row sums of exp2(s*scale2); 64-col chunks for MLP/ILP ----
  float sum4[4] = {0.f, 0.f, 0.f, 0.f};
  const int p1end = qrow0 + 16;           // cols < p1end (multiple of 16)
  const int nfull = p1end >> 6;
  for (int kc6 = 0; kc6 < nfull; ++kc6) {
    const int kc = kc6 << 6;
    bf16x8 b0[4], b1[4];
#pragma unroll
    for (int tt = 0; tt < 4; ++tt) {
      b0[tt] = *(const bf16x8*)&Kh[(kc + tt * 16 + lo) * 64 + qd * 8];
      b1[tt] = *(const bf16x8*)&Kh[(kc + tt * 16 + lo) * 64 + 32 + qd * 8];
    }
    f32x4 st[4];
#pragma unroll
    for (int tt = 0; tt < 4; ++tt) {
      f32x4 s = (f32x4){0.f, 0.f, 0.f, 0.f};
      s = MFMA16(aq0, b0[tt], s);
      s = MFMA16(aq1, b1[tt], s);
      st[tt] = s;
    }
#pragma unroll
    for (int tt = 0; tt < 4; ++tt) {
      const int col = kc + tt * 16 + lo;
#pragma unroll
      for (int r = 0; r < 4; ++r) {
        const int row = qrow0 + qd * 4 + r;
        if (col <= row) sum4[r] += exp2f(st[tt][r] * scale2);
      }
    }
  }
  for (int kb = nfull << 6; kb < p1end; kb += 16) {   // <=3 tail tiles
    bf16x8 b0 = *(const bf16x8*)&Kh[(kb + lo) * 64 + qd * 8];
    bf16x8 b1 = *(const bf16x8*)&Kh[(kb + lo) * 64 + 32 + qd * 8];
    f32x4 s = (f32x4){0.f, 0.f, 0.f, 0.f};
    s = MFMA16(aq0, b0, s);
    s = MFMA16(aq1, b1, s);
    const int col = kb + lo;
#pragma unroll
    for (int r = 0; r < 4; ++r) {
      const int row = qrow0 + qd * 4 + r;
      if (col <= row) sum4[r] += exp2f(s[r] * scale2);
    }
  }
  for (int off = 1; off < 16; off <<= 1)
    for (int r = 0; r < 4; r++) sum4[r] += __shfl_xor(sum4[r], off, 64);
  float rinv[4];
  for (int r = 0; r < 4; r++) rinv[r] = 1.f / sum4[r];

  // ---- phase 2: recompute, normalize, write attn, PV accumulate ----
  f32x4 oacc[4];
  for (int i = 0; i < 4; i++) oacc[i] = (f32x4){0.f, 0.f, 0.f, 0.f};
  const int kcend = ((qrow0 + 16 + 31) >> 5) << 5;  // ceil to 32
  u16* Pw = &Plds[w][0];
  for (int kc = 0; kc < kcend; kc += 32) {
    // V loads issued first: independent of P, latency hides under QK+softmax
    bf16x8 vf0 = *(const bf16x8*)&Vh[(size_t)(0 * 16 + lo) * 2048 + kc + qd * 8];
    bf16x8 vf1 = *(const bf16x8*)&Vh[(size_t)(1 * 16 + lo) * 2048 + kc + qd * 8];
    bf16x8 vf2 = *(const bf16x8*)&Vh[(size_t)(2 * 16 + lo) * 2048 + kc + qd * 8];
    bf16x8 vf3 = *(const bf16x8*)&Vh[(size_t)(3 * 16 + lo) * 2048 + kc + qd * 8];
    bf16x8 kb00 = *(const bf16x8*)&Kh[(kc + lo) * 64 + qd * 8];
    bf16x8 kb01 = *(const bf16x8*)&Kh[(kc + lo) * 64 + 32 + qd * 8];
    bf16x8 kb10 = *(const bf16x8*)&Kh[(kc + 16 + lo) * 64 + qd * 8];
    bf16x8 kb11 = *(const bf16x8*)&Kh[(kc + 16 + lo) * 64 + 32 + qd * 8];
    f32x4 s0 = (f32x4){0.f, 0.f, 0.f, 0.f};
    f32x4 s1 = (f32x4){0.f, 0.f, 0.f, 0.f};
    s0 = MFMA16(aq0, kb00, s0);
    s0 = MFMA16(aq1, kb01, s0);
    s1 = MFMA16(aq0, kb10, s1);
    s1 = MFMA16(aq1, kb11, s1);
#pragma unroll
    for (int r = 0; r < 4; ++r) {
      const int row = qrow0 + qd * 4 + r;
      const int c0 = kc + lo, c1 = kc + 16 + lo;
      const float p0 = (c0 <= row) ? exp2f(s0[r] * scale2) * rinv[r] : 0.f;
      const float p1 = (c1 <= row) ? exp2f(s1[r] * scale2) * rinv[r] : 0.f;
      Ah[(size_t)row * 2048 + c0] = p0;
      Ah[(size_t)row * 2048 + c1] = p1;
      Pw[(qd * 4 + r) * 40 + lo] = f2bf(p0);
      Pw[(qd * 4 + r) * 40 + 16 + lo] = f2bf(p1);
    }
    bf16x8 pf = *(const bf16x8*)&Pw[lo * 40 + qd * 8];  // A-frag: P[q=lo][k=qd*8+j]
    oacc[0] = MFMA16(pf, vf0, oacc[0]);
    oacc[1] = MFMA16(pf, vf1, oacc[1]);
    oacc[2] = MFMA16(pf, vf2, oacc[2]);
    oacc[3] = MFMA16(pf, vf3, oacc[3]);
  }

  // ---- context store: ctx[b*2048+s][h*64+d] bf16 ----
  const int bb = bh >> 4, h = bh & 15;
  for (int d0 = 0; d0 < 4; ++d0)
    for (int r = 0; r < 4; r++) {
      const int row = qrow0 + qd * 4 + r;
      ctx[(size_t)(bb * 2048 + row) * 1024 + h * 64 + d0 * 16 + lo] =
          f2bf(oacc[d0][r]);
    }
}

extern "C" void kernel_launch(void* const* d_in, const int* in_sizes, int n_in,
                              void* d_out, int out_size, void* d_ws, size_t ws_size,
                              hipStream_t stream) {
  const float* query = (const float*)d_in[0];
  const float* key   = (const float*)d_in[1];
  const float* value = (const float*)d_in[2];
  // d_in[3] = mask: always causal tril -> implemented directly
  const float* wq = (const float*)d_in[4];
  const float* bq = (const float*)d_in[5];
  const float* wk = (const float*)d_in[6];
  const float* bk = (const float*)d_in[7];
  const float* wv = (const float*)d_in[8];
  const float* bv = (const float*)d_in[9];
  const float* wo = (const float*)d_in[10];
  const float* bo = (const float*)d_in[11];

  char* ws = (char*)d_ws;
  const size_t MB = 1024 * 1024;
  u16* Xq = (u16*)(ws + 0 * MB);    // 16 MiB each
  u16* Xk = (u16*)(ws + 16 * MB);
  u16* Xv = (u16*)(ws + 32 * MB);
  u16* Wq = (u16*)(ws + 48 * MB);   // 2 MiB each
  u16* Wk = (u16*)(ws + 50 * MB);
  u16* Wv = (u16*)(ws + 52 * MB);
  u16* Wo = (u16*)(ws + 54 * MB);
  u16* Qb = (u16*)(ws + 56 * MB);   // [b,h,s,d] bf16, 16 MiB
  u16* Kb = (u16*)(ws + 72 * MB);
  u16* Vtb = (u16*)(ws + 88 * MB);  // [b,h,d,s]
  u16* ctx = Xq;                    // reuse: X buffers dead after projections

  // bf16 conversions
  cvt_bf16_kernel<<<8192, 256, 0, stream>>>(query, Xq, 2097152);
  cvt_bf16_kernel<<<8192, 256, 0, stream>>>(key, Xk, 2097152);
  cvt_bf16_kernel<<<8192, 256, 0, stream>>>(value, Xv, 2097152);
  cvt_bf16_kernel<<<1024, 256, 0, stream>>>(wq, Wq, 262144);
  cvt_bf16_kernel<<<1024, 256, 0, stream>>>(wk, Wk, 262144);
  cvt_bf16_kernel<<<1024, 256, 0, stream>>>(wv, Wv, 262144);
  cvt_bf16_kernel<<<1024, 256, 0, stream>>>(wo, Wo, 262144);

  dim3 gg(64, 8);
  gemm_bt_kernel<0><<<gg, 256, 0, stream>>>(Xq, Wq, bq, Qb);
  gemm_bt_kernel<0><<<gg, 256, 0, stream>>>(Xk, Wk, bk, Kb);
  gemm_bt_kernel<2><<<gg, 256, 0, stream>>>(Xv, Wv, bv, Vtb);

  float* out = (float*)d_out;
  float* attn = out + (size_t)8192 * 1024;

  zero_upper_kernel<<<dim3(512, 64), 256, 0, stream>>>(attn);
  attn_fused_kernel<<<dim3(32, 64), 256, 0, stream>>>(Qb, Kb, Vtb, attn, ctx);

  gemm_bt_kernel<3><<<gg, 256, 0, stream>>>(ctx, Wo, bo, (void*)out);
}

// Round 3
// 1591.392 us; speedup vs baseline: 1.1807x; 1.1230x over previous
//
#include <hip/hip_runtime.h>

typedef unsigned short u16;
typedef __attribute__((ext_vector_type(8))) short bf16x8;   // 8 bf16 in 4 VGPRs
typedef __attribute__((ext_vector_type(4))) float f32x4;

#define MFMA16(a, b, c) __builtin_amdgcn_mfma_f32_16x16x32_bf16((a), (b), (c), 0, 0, 0)

// async global->LDS, 16B per lane; LDS dest = wave-uniform base + lane*16
#define GLL(gp, lp)                                                         \
  __builtin_amdgcn_global_load_lds(                                         \
      (const __attribute__((address_space(1))) void*)(const void*)(gp),     \
      (__attribute__((address_space(3))) void*)(void*)(lp), 16, 0, 0)

__device__ __forceinline__ u16 f2bf(float f) {
  union { float f; unsigned u; } c; c.f = f;
  unsigned r = c.u + 0x7FFFu + ((c.u >> 16) & 1u);   // RNE
  return (u16)(r >> 16);
}

// ---------------- fp32 -> bf16 conversion (vectorized) ----------------
__global__ __launch_bounds__(256) void cvt_bf16_kernel(
    const float* __restrict__ in, u16* __restrict__ out, int n4) {
  int i = blockIdx.x * 256 + threadIdx.x;
  if (i < n4) {
    float4 v = ((const float4*)in)[i];
    ushort4 o;
    o.x = f2bf(v.x); o.y = f2bf(v.y); o.z = f2bf(v.z); o.w = f2bf(v.w);
    ((ushort4*)out)[i] = o;
  }
}

// ---------------- GEMM: C[m,n] = sum_k A[m,k]*Bw[n,k] + bias[n] ----------------
// M=8192 (64*128), N=1024 (8*128), K=1024. A,Bw bf16 row-major [*,1024].
// MODE 0: store bf16 to [b,h,s,d]   (Q,K)    m=b*2048+s, n=h*64+d
// MODE 2: store bf16 to [b,h,d,s]   (V^T) via LDS-transposed coalesced epilogue
// MODE 3: store fp32 to row-major [m,1024]   (final output)
template <int MODE>
__global__ __launch_bounds__(256) void gemm_bt_kernel(
    const u16* __restrict__ A, const u16* __restrict__ Bw,
    const float* __restrict__ bias, void* __restrict__ Cout) {
  constexpr int Kd = 1024;
  __shared__ u16 sA[128 * 32];
  __shared__ u16 sB[128 * 32];
  const int t = threadIdx.x;
  // XCD-aware swizzle: 512 blocks = 8 XCDs x 64; XCD g owns bx in [g*8, g*8+8)
  const int wg = blockIdx.x + (blockIdx.y << 6);
  const int swz = ((wg & 7) << 6) | (wg >> 3);
  const int m0 = (swz >> 3) * 128;
  const int n0 = (swz & 7) * 128;
  const int w = t >> 6, lane = t & 63, lo = lane & 15, qd = lane >> 4;

  f32x4 acc[4][4];
  for (int i = 0; i < 4; i++)
    for (int j = 0; j < 4; j++) acc[i][j] = (f32x4){0.f, 0.f, 0.f, 0.f};

  // staging: chunk c covers row c>>2, cols (c&3)*8..+7 ; thread t does c=t and c=t+256
  const int r0 = t >> 2, q0 = (t & 3) * 8;
  const u16* gA0 = A + (size_t)(m0 + r0) * Kd + q0;
  const u16* gA1 = A + (size_t)(m0 + r0 + 64) * Kd + q0;
  const u16* gB0 = Bw + (size_t)(n0 + r0) * Kd + q0;
  const u16* gB1 = Bw + (size_t)(n0 + r0 + 64) * Kd + q0;
  u16* lA0 = &sA[(t & ~63) * 8];
  u16* lA1 = &sA[((t + 256) & ~63) * 8];
  u16* lB0 = &sB[(t & ~63) * 8];
  u16* lB1 = &sB[((t + 256) & ~63) * 8];

  const int am = (w & 1) * 64, bn = (w >> 1) * 64;

  for (int kb = 0; kb < Kd; kb += 32) {
    GLL(gA0 + kb, lA0);
    GLL(gA1 + kb, lA1);
    GLL(gB0 + kb, lB0);
    GLL(gB1 + kb, lB1);
    __syncthreads();
    bf16x8 af[4], bfv[4];
    for (int i = 0; i < 4; i++)
      af[i] = *(const bf16x8*)&sA[(am + i * 16 + lo) * 32 + qd * 8];
    for (int j = 0; j < 4; j++)
      bfv[j] = *(const bf16x8*)&sB[(bn + j * 16 + lo) * 32 + qd * 8];
    for (int i = 0; i < 4; i++)
      for (int j = 0; j < 4; j++) acc[i][j] = MFMA16(af[i], bfv[j], acc[i][j]);
    __syncthreads();
  }

  if constexpr (MODE == 2) {
    // LDS-transposed epilogue: stage [n_local][m_local] bf16, then store
    // coalesced runs along s.  Old path did 2B stores at 4KB lane stride.
    __shared__ u16 sT[64 * 136];   // stride 136 u16 = 272B, 16B-aligned rows
    const int bb = m0 >> 11;       // batch constant per block (128 | 2048)
    const int s0 = m0 & 2047;
    const int h0 = n0 >> 6;
    for (int half = 0; half < 2; ++half) {
      __syncthreads();
      if ((w >> 1) == half) {      // waves whose bn == half*64
        for (int j = 0; j < 4; j++) {
          const float bval = bias[n0 + half * 64 + j * 16 + lo];
          for (int i = 0; i < 4; i++)
            for (int r = 0; r < 4; r++)
              sT[(j * 16 + lo) * 136 + am + i * 16 + qd * 4 + r] =
                  f2bf(acc[i][j][r] + bval);
        }
      }
      __syncthreads();
      // copy 64 rows (d = nr) x 128 u16 (s run) to global: [b,h,d,s]
      const int nr = t >> 2;
      u16* dst = (u16*)Cout +
                 ((size_t)((bb * 16 + h0 + half) * 64 + nr)) * 2048 + s0;
      for (int c = 0; c < 4; ++c) {
        const int ch = (t & 3) + c * 4;   // 16B chunk index 0..15
        *(uint4*)(dst + ch * 8) = *(const uint4*)(&sT[nr * 136 + ch * 8]);
      }
    }
  } else {
    for (int i = 0; i < 4; i++)
      for (int j = 0; j < 4; j++) {
        const int n = n0 + bn + j * 16 + lo;
        const float bval = bias[n];
        for (int r = 0; r < 4; r++) {
          const int m = m0 + am + i * 16 + qd * 4 + r;
          float v = acc[i][j][r] + bval;
          if constexpr (MODE == 3) {
            // final output, never re-read on device: bypass L2
            __builtin_nontemporal_store(v, &((float*)Cout)[(size_t)m * 1024 + n]);
          } else {  // MODE 0: [b,h,s,d]
            const int bb = m >> 11, s = m & 2047, h = n >> 6, d = n & 63;
            ((u16*)Cout)[((size_t)(bb * 16 + h) * 2048 + s) * 64 + d] = f2bf(v);
          }
        }
      }
  }
}

// ---------------- zero the strictly-masked attn region ----------------
// For row r the attn kernel writes cols [0, kz(r)); this fills [kz(r), 2048).
__global__ __launch_bounds__(256) void zero_upper_kernel(float* __restrict__ attn) {
  const int t = threadIdx.x, w = t >> 6, lane = t & 63;
  const int row = blockIdx.x * 4 + w;
  float* rowp = attn + ((size_t)blockIdx.y * 2048 + row) * 2048;
  const int kz = ((((row >> 4) << 4) + 47) >> 5) << 5;   // == kcend of row's wave
  const f32x4 z4 = (f32x4){0.f, 0.f, 0.f, 0.f};
  for (int c = kz + lane * 4; c < 2048; c += 256)
    __builtin_nontemporal_store(z4, (f32x4*)(rowp + c));
}

// ---------------- fused causal attention ----------------
// grid: (16 tile-pairs, 64 b*h), XCD-swizzled so each XCD owns 8 bh
// (K+Vt = 4MB = one L2).  Block = 4 waves; wave w owns q-rows qt*64+w*16..+15.
// Each block processes the BALANCED pair {31-qb, qb}: per-block work is
// constant (33 units), so all 1024 blocks are uniform -> no straggler tail
// (round-0 OccupancyPercent=23% was the tail signature).
// attn-prob stores are nontemporal so the K/Vt L2 working set survives.
// Q,K: [b,h,s,64] bf16 ; Vt: [b,h,64,s] bf16 ; attn fp32 ; ctx bf16 [8192,1024]
__global__ __launch_bounds__(256) void attn_fused_kernel(
    const u16* __restrict__ Q, const u16* __restrict__ K,
    const u16* __restrict__ Vt, float* __restrict__ attn,
    u16* __restrict__ ctx) {
  __shared__ u16 Plds[4][16 * 40];  // per-wave P staging, stride 40 kills conflicts
  const int wg = blockIdx.x + (blockIdx.y << 4);          // 0..1023
  const int swz = ((wg & 7) << 7) | (wg >> 3);            // bijective, 1024 = 8*128
  const int qb = swz & 15, bh = swz >> 4;
  const int t = threadIdx.x, w = t >> 6, lane = t & 63, lo = lane & 15, qd = lane >> 4;
  const u16* Qh = Q + (size_t)bh * 2048 * 64;
  const u16* Kh = K + (size_t)bh * 2048 * 64;
  const u16* Vh = Vt + (size_t)bh * 64 * 2048;
  float* Ah = attn + (size_t)bh * 2048 * 2048;
  const int bb = bh >> 4, h = bh & 15;
  const float scale2 = 0.125f * 1.44269504088896f;  // log2(e)/sqrt(64)

#pragma unroll 1
  for (int ti = 0; ti < 2; ++ti) {
    const int qt = ti ? qb : (31 - qb);
    const int qrow0 = qt * 64 + w * 16;

    bf16x8 aq0 = *(const bf16x8*)&Qh[(qrow0 + lo) * 64 + qd * 8];
    bf16x8 aq1 = *(const bf16x8*)&Qh[(qrow0 + lo) * 64 + 32 + qd * 8];

    // ---- phase 1: row sums of exp2(s*scale2); 64-col chunks for MLP/ILP ----
    float sum4[4] = {0.f, 0.f, 0.f, 0.f};
    const int p1end = qrow0 + 16;           // cols < p1end (multiple of 16)
    const int nfull = p1end >> 6;
    for (int kc6 = 0; kc6 < nfull; ++kc6) {
      const int kc = kc6 << 6;
      bf16x8 b0[4], b1[4];
#pragma unroll
      for (int tt = 0; tt < 4; ++tt) {
        b0[tt] = *(const bf16x8*)&Kh[(kc + tt * 16 + lo) * 64 + qd * 8];
        b1[tt] = *(const bf16x8*)&Kh[(kc + tt * 16 + lo) * 64 + 32 + qd * 8];
      }
      f32x4 st[4];
#pragma unroll
      for (int tt = 0; tt < 4; ++tt) {
        f32x4 s = (f32x4){0.f, 0.f, 0.f, 0.f};
        s = MFMA16(aq0, b0[tt], s);
        s = MFMA16(aq1, b1[tt], s);
        st[tt] = s;
      }
#pragma unroll
      for (int tt = 0; tt < 4; ++tt) {
        const int col = kc + tt * 16 + lo;
#pragma unroll
        for (int r = 0; r < 4; ++r) {
          const int row = qrow0 + qd * 4 + r;
          if (col <= row) sum4[r] += exp2f(st[tt][r] * scale2);
        }
      }
    }
    for (int kb = nfull << 6; kb < p1end; kb += 16) {   // <=3 tail tiles
      bf16x8 b0 = *(const bf16x8*)&Kh[(kb + lo) * 64 + qd * 8];
      bf16x8 b1 = *(const bf16x8*)&Kh[(kb + lo) * 64 + 32 + qd * 8];
      f32x4 s = (f32x4){0.f, 0.f, 0.f, 0.f};
      s = MFMA16(aq0, b0, s);
      s = MFMA16(aq1, b1, s);
      const int col = kb + lo;
#pragma unroll
      for (int r = 0; r < 4; ++r) {
        const int row = qrow0 + qd * 4 + r;
        if (col <= row) sum4[r] += exp2f(s[r] * scale2);
      }
    }
    for (int off = 1; off < 16; off <<= 1)
      for (int r = 0; r < 4; r++) sum4[r] += __shfl_xor(sum4[r], off, 64);
    float rinv[4];
    for (int r = 0; r < 4; r++) rinv[r] = 1.f / sum4[r];

    // ---- phase 2: recompute, normalize, write attn, PV accumulate ----
    f32x4 oacc[4];
    for (int i = 0; i < 4; i++) oacc[i] = (f32x4){0.f, 0.f, 0.f, 0.f};
    const int kcend = ((qrow0 + 16 + 31) >> 5) << 5;  // ceil to 32
    u16* Pw = &Plds[w][0];
    for (int kc = 0; kc < kcend; kc += 32) {
      // V loads issued first: independent of P, latency hides under QK+softmax
      bf16x8 vf0 = *(const bf16x8*)&Vh[(size_t)(0 * 16 + lo) * 2048 + kc + qd * 8];
      bf16x8 vf1 = *(const bf16x8*)&Vh[(size_t)(1 * 16 + lo) * 2048 + kc + qd * 8];
      bf16x8 vf2 = *(const bf16x8*)&Vh[(size_t)(2 * 16 + lo) * 2048 + kc + qd * 8];
      bf16x8 vf3 = *(const bf16x8*)&Vh[(size_t)(3 * 16 + lo) * 2048 + kc + qd * 8];
      bf16x8 kb00 = *(const bf16x8*)&Kh[(kc + lo) * 64 + qd * 8];
      bf16x8 kb01 = *(const bf16x8*)&Kh[(kc + lo) * 64 + 32 + qd * 8];
      bf16x8 kb10 = *(const bf16x8*)&Kh[(kc + 16 + lo) * 64 + qd * 8];
      bf16x8 kb11 = *(const bf16x8*)&Kh[(kc + 16 + lo) * 64 + 32 + qd * 8];
      f32x4 s0 = (f32x4){0.f, 0.f, 0.f, 0.f};
      f32x4 s1 = (f32x4){0.f, 0.f, 0.f, 0.f};
      s0 = MFMA16(aq0, kb00, s0);
      s0 = MFMA16(aq1, kb01, s0);
      s1 = MFMA16(aq0, kb10, s1);
      s1 = MFMA16(aq1, kb11, s1);
#pragma unroll
      for (int r = 0; r < 4; ++r) {
        const int row = qrow0 + qd * 4 + r;
        const int c0 = kc + lo, c1 = kc + 16 + lo;
        const float p0 = (c0 <= row) ? exp2f(s0[r] * scale2) * rinv[r] : 0.f;
        const float p1 = (c1 <= row) ? exp2f(s1[r] * scale2) * rinv[r] : 0.f;
        __builtin_nontemporal_store(p0, &Ah[(size_t)row * 2048 + c0]);
        __builtin_nontemporal_store(p1, &Ah[(size_t)row * 2048 + c1]);
        Pw[(qd * 4 + r) * 40 + lo] = f2bf(p0);
        Pw[(qd * 4 + r) * 40 + 16 + lo] = f2bf(p1);
      }
      bf16x8 pf = *(const bf16x8*)&Pw[lo * 40 + qd * 8];  // A-frag: P[q=lo][k=qd*8+j]
      oacc[0] = MFMA16(pf, vf0, oacc[0]);
      oacc[1] = MFMA16(pf, vf1, oacc[1]);
      oacc[2] = MFMA16(pf, vf2, oacc[2]);
      oacc[3] = MFMA16(pf, vf3, oacc[3]);
    }

    // ---- context store: ctx[b*2048+s][h*64+d] bf16 ----
    for (int d0 = 0; d0 < 4; ++d0)
      for (int r = 0; r < 4; r++) {
        const int row = qrow0 + qd * 4 + r;
        ctx[(size_t)(bb * 2048 + row) * 1024 + h * 64 + d0 * 16 + lo] =
            f2bf(oacc[d0][r]);
      }
  }
}

extern "C" void kernel_launch(void* const* d_in, const int* in_sizes, int n_in,
                              void* d_out, int out_size, void* d_ws, size_t ws_size,
                              hipStream_t stream) {
  const float* query = (const float*)d_in[0];
  const float* key   = (const float*)d_in[1];
  const float* value = (const float*)d_in[2];
  // d_in[3] = mask: always causal tril -> implemented directly
  const float* wq = (const float*)d_in[4];
  const float* bq = (const float*)d_in[5];
  const float* wk = (const float*)d_in[6];
  const float* bk = (const float*)d_in[7];
  const float* wv = (const float*)d_in[8];
  const float* bv = (const float*)d_in[9];
  const float* wo = (const float*)d_in[10];
  const float* bo = (const float*)d_in[11];

  char* ws = (char*)d_ws;
  const size_t MB = 1024 * 1024;
  u16* Xq = (u16*)(ws + 0 * MB);    // 16 MiB each
  u16* Xk = (u16*)(ws + 16 * MB);
  u16* Xv = (u16*)(ws + 32 * MB);
  u16* Wq = (u16*)(ws + 48 * MB);   // 2 MiB each
  u16* Wk = (u16*)(ws + 50 * MB);
  u16* Wv = (u16*)(ws + 52 * MB);
  u16* Wo = (u16*)(ws + 54 * MB);
  u16* Qb = (u16*)(ws + 56 * MB);   // [b,h,s,d] bf16, 16 MiB
  u16* Kb = (u16*)(ws + 72 * MB);
  u16* Vtb = (u16*)(ws + 88 * MB);  // [b,h,d,s]
  u16* ctx = Xq;                    // reuse: X buffers dead after projections

  // bf16 conversions
  cvt_bf16_kernel<<<8192, 256, 0, stream>>>(query, Xq, 2097152);
  cvt_bf16_kernel<<<8192, 256, 0, stream>>>(key, Xk, 2097152);
  cvt_bf16_kernel<<<8192, 256, 0, stream>>>(value, Xv, 2097152);
  cvt_bf16_kernel<<<1024, 256, 0, stream>>>(wq, Wq, 262144);
  cvt_bf16_kernel<<<1024, 256, 0, stream>>>(wk, Wk, 262144);
  cvt_bf16_kernel<<<1024, 256, 0, stream>>>(wv, Wv, 262144);
  cvt_bf16_kernel<<<1024, 256, 0, stream>>>(wo, Wo, 262144);

  dim3 gg(64, 8);
  gemm_bt_kernel<0><<<gg, 256, 0, stream>>>(Xq, Wq, bq, Qb);
  gemm_bt_kernel<0><<<gg, 256, 0, stream>>>(Xk, Wk, bk, Kb);
  gemm_bt_kernel<2><<<gg, 256, 0, stream>>>(Xv, Wv, bv, Vtb);

  float* out = (float*)d_out;
  float* attn = out + (size_t)8192 * 1024;

  zero_upper_kernel<<<dim3(512, 64), 256, 0, stream>>>(attn);
  attn_fused_kernel<<<dim3(16, 64), 256, 0, stream>>>(Qb, Kb, Vtb, attn, ctx);

  gemm_bt_kernel<3><<<gg, 256, 0, stream>>>(ctx, Wo, bo, (void*)out);
}